// Round 4
// baseline (4627.918 us; speedup 1.0000x reference)
//
#include <hip/hip_runtime.h>

// MI-LSTM on MI355X (gfx950). I/O is FP32 (per reference dtypes); compute
// uses bf16 MFMA internally (test tolerance is bf16-grade: 1.156e-2).
// B=128, T=256, D_IN=1024, UNITS=1024, N_CLASS=1024.
//
// Structure:
//   1) transpose+convert Wk,Wr,Wc (fp32 [K][N]) -> bf16 [N][K] in ws
//   2) loop over time-chunks of TC (adaptive to ws_size):
//        XPc[b*TC+tt][4096] = x[b][t0+tt] @ Wk + bk  (bf16 MFMA, x converted
//        on the fly during LDS staging; XPc stored bf16)
//        TC x step kernel: hp = h @ Wr (direct-global bf16 MFMA frags),
//        fused MI gates; h carried bf16, c carried fp32
//   3) out = h @ Wc + bc (fp32 out); emit (out, h, c) fp32 into d_out

typedef unsigned short u16;
typedef __attribute__((ext_vector_type(8))) short short8;   // 8 x bf16 (4 VGPRs)
typedef __attribute__((ext_vector_type(4))) float f32x4;    // MFMA accumulator

#define B_SZ   128
#define T_SZ   256
#define D_IN   1024
#define UNITS  1024
#define FOURU  4096

__device__ __forceinline__ float bf2f(u16 h) {
    return __uint_as_float(((unsigned int)h) << 16);
}
__device__ __forceinline__ u16 f2bf(float f) {
    unsigned int u = __float_as_uint(f);
    u += 0x7fffu + ((u >> 16) & 1u);   // round-to-nearest-even
    return (u16)(u >> 16);
}
__device__ __forceinline__ float sigmoidf_(float x) {
    return 1.0f / (1.0f + __expf(-x));
}

// ---------------------------------------------------------------- transpose+cvt
// out[n][k] = bf16(in[k][n]);  in is fp32 [K][N] row-major.
__global__ __launch_bounds__(256) void transpose_cvt(
    const float* __restrict__ in, u16* __restrict__ out, int K, int N)
{
    __shared__ u16 t[32][33];
    int n0 = blockIdx.x * 32, k0 = blockIdx.y * 32;
    int c = threadIdx.x & 31, r = threadIdx.x >> 5;   // r in 0..7
    #pragma unroll
    for (int i = 0; i < 4; ++i) {
        int kk = r + i * 8;
        t[kk][c] = f2bf(in[(size_t)(k0 + kk) * N + n0 + c]);
    }
    __syncthreads();
    #pragma unroll
    for (int i = 0; i < 4; ++i) {
        int nn = r + i * 8;
        out[(size_t)(n0 + nn) * K + k0 + c] = t[c][nn];
    }
}

// ---------------------------------------------------------------- XP GEMM (one time-chunk)
// Cc[b*tc+tt][n] = bf16( x[b][t0+tt][:] @ Wk + bk ),  tt in [0,tc).
// X is fp32 (converted to bf16 during staging); Bt = WkT bf16 [4096][1024].
// 128x128 tile, BK=32. grid = (tc, 32) blocks of 256.
__global__ __launch_bounds__(256) void gemm_xp_chunk(
    const float* __restrict__ X, const u16* __restrict__ Bt,
    const float* __restrict__ bias, u16* __restrict__ Cc,
    int t0, int tcShift)
{
    __shared__ __align__(16) u16 As[128 * 40];   // stride 40 elems breaks pow-2 bank stride
    __shared__ __align__(16) u16 Bs[128 * 40];
    int tid = threadIdx.x;
    int wave = tid >> 6, lane = tid & 63;
    int bm = blockIdx.x * 128;     // row' base, row' = b*tc + tt
    int bn = blockIdx.y * 128;
    int wm = (wave & 1) * 64, wn = (wave >> 1) * 64;
    int lm = lane & 15, lq = lane >> 4;
    int tcMask = (1 << tcShift) - 1;

    f32x4 acc[4][4] = {};

    for (int k0 = 0; k0 < D_IN; k0 += 32) {
        #pragma unroll
        for (int i = 0; i < 2; ++i) {
            int idx = tid + i * 256;
            int r = idx >> 2, q = idx & 3;
            int rowp = bm + r;
            int b = rowp >> tcShift;
            int tt = rowp & tcMask;
            const float* xs = &X[(size_t)(b * T_SZ + t0 + tt) * D_IN + k0 + q * 8];
            float4 f0 = *(const float4*)xs;
            float4 f1 = *(const float4*)(xs + 4);
            uint4 v;
            v.x = (unsigned)f2bf(f0.x) | ((unsigned)f2bf(f0.y) << 16);
            v.y = (unsigned)f2bf(f0.z) | ((unsigned)f2bf(f0.w) << 16);
            v.z = (unsigned)f2bf(f1.x) | ((unsigned)f2bf(f1.y) << 16);
            v.w = (unsigned)f2bf(f1.z) | ((unsigned)f2bf(f1.w) << 16);
            *(uint4*)&As[r * 40 + q * 8] = v;
            *(uint4*)&Bs[r * 40 + q * 8] =
                *(const uint4*)&Bt[(size_t)(bn + r) * D_IN + k0 + q * 8];
        }
        __syncthreads();
        short8 af[4], bf[4];
        #pragma unroll
        for (int t = 0; t < 4; ++t) {
            af[t] = *(const short8*)&As[(wm + t * 16 + lm) * 40 + lq * 8];
            bf[t] = *(const short8*)&Bs[(wn + t * 16 + lm) * 40 + lq * 8];
        }
        #pragma unroll
        for (int mt = 0; mt < 4; ++mt)
            #pragma unroll
            for (int nt = 0; nt < 4; ++nt)
                acc[mt][nt] = __builtin_amdgcn_mfma_f32_16x16x32_bf16(
                    af[mt], bf[nt], acc[mt][nt], 0, 0, 0);
        __syncthreads();
    }

    #pragma unroll
    for (int mt = 0; mt < 4; ++mt) {
        #pragma unroll
        for (int nt = 0; nt < 4; ++nt) {
            int col = bn + wn + nt * 16 + lm;
            float bv = bias[col];
            #pragma unroll
            for (int r = 0; r < 4; ++r) {
                int rowp = bm + wm + mt * 16 + lq * 4 + r;
                Cc[(size_t)rowp * FOURU + col] = f2bf(acc[mt][nt][r] + bv);
            }
        }
    }
}

// ---------------------------------------------------------------- LSTM step
// Per block: 16 rows x 32 u-cols, all 4 gates (wave g = gate g, 2 n-tiles).
// hp = h @ Wr read as direct-global bf16 MFMA fragments (WrT [4096][1024]).
// XPtt = XPc + tt*4096 (bf16); per-batch stride bStride = tc*4096.
__global__ __launch_bounds__(256) void milstm_step(
    const u16* __restrict__ XPtt,
    const u16* __restrict__ WrT,
    const float* __restrict__ br,
    const float* __restrict__ alpha,
    const float* __restrict__ beta1,
    const float* __restrict__ beta2,
    const u16* __restrict__ h_in,    // [128][1024] bf16
    const float* __restrict__ c_in,  // [128][1024] f32
    u16* __restrict__ h_out,         // [128][1024] bf16
    float* __restrict__ c_out,       // same buffer as c_in is fine
    int bStride)
{
    __shared__ float zbuf[4][16][33];
    int tid = threadIdx.x;
    int gate = tid >> 6, lane = tid & 63;
    int bx = blockIdx.x;              // 256 blocks: 8 row-tiles x 32 u-tiles
    int row0 = (bx & 7) * 16;
    int u0 = (bx >> 3) * 32;
    int lm = lane & 15, lq = lane >> 4;

    f32x4 acc0 = {}, acc1 = {};
    const u16* Arow = &h_in[(size_t)(row0 + lm) * UNITS];
    const u16* B0 = &WrT[(size_t)(gate * UNITS + u0 + lm) * UNITS];
    const u16* B1 = B0 + (size_t)16 * UNITS;

    #pragma unroll 8
    for (int k0 = 0; k0 < UNITS; k0 += 32) {
        short8 a  = *(const short8*)&Arow[k0 + lq * 8];
        short8 b0 = *(const short8*)&B0[k0 + lq * 8];
        short8 b1 = *(const short8*)&B1[k0 + lq * 8];
        acc0 = __builtin_amdgcn_mfma_f32_16x16x32_bf16(a, b0, acc0, 0, 0, 0);
        acc1 = __builtin_amdgcn_mfma_f32_16x16x32_bf16(a, b1, acc1, 0, 0, 0);
    }

    #pragma unroll
    for (int nt = 0; nt < 2; ++nt) {
        f32x4 acc = nt ? acc1 : acc0;
        int ucol = nt * 16 + lm;                // 0..31
        int n = gate * UNITS + u0 + ucol;
        float brv = br[n];
        float al  = alpha[n];
        float b1v = beta1[n];
        float b2v = beta2[n];
        #pragma unroll
        for (int r = 0; r < 4; ++r) {
            int row = lq * 4 + r;               // 0..15 (batch row in tile)
            float hp = acc[r] + brv;
            float xp = bf2f(XPtt[(size_t)(row0 + row) * bStride + n]);
            zbuf[gate][row][ucol] = al * xp * hp + b1v * xp + b2v * hp;
        }
    }
    __syncthreads();

    #pragma unroll
    for (int e = 0; e < 2; ++e) {
        int idx = tid + e * 256;                // 0..511
        int row = idx >> 5, u = idx & 31;
        float zi = zbuf[0][row][u];
        float zf = zbuf[1][row][u];
        float zg = zbuf[2][row][u];
        float zo = zbuf[3][row][u];
        size_t gi = (size_t)(row0 + row) * UNITS + u0 + u;
        float c = c_in[gi];
        float cn = tanhf(zg) * sigmoidf_(zi) + c * sigmoidf_(zf);
        c_out[gi] = cn;
        h_out[gi] = f2bf(tanhf(cn) * sigmoidf_(zo));
    }
}

// ---------------------------------------------------------------- final GEMM
// out[128][1024] = h @ Wc + bc (fp32 out); WcT bf16 [1024][1024].
__global__ __launch_bounds__(256) void gemm_out(
    const u16* __restrict__ h, const u16* __restrict__ WcT,
    const float* __restrict__ bc, float* __restrict__ out)
{
    int tid = threadIdx.x;
    int wave = tid >> 6, lane = tid & 63;
    int bx = blockIdx.x;               // 128 blocks: 8 row-tiles x 16 col-grps
    int row0 = (bx & 7) * 16;
    int n0 = (bx >> 3) * 64 + wave * 16;
    int lm = lane & 15, lq = lane >> 4;

    f32x4 acc = {};
    const u16* Arow = &h[(size_t)(row0 + lm) * UNITS];
    const u16* Brow = &WcT[(size_t)(n0 + lm) * UNITS];
    #pragma unroll 8
    for (int k0 = 0; k0 < UNITS; k0 += 32) {
        short8 a = *(const short8*)&Arow[k0 + lq * 8];
        short8 b = *(const short8*)&Brow[k0 + lq * 8];
        acc = __builtin_amdgcn_mfma_f32_16x16x32_bf16(a, b, acc, 0, 0, 0);
    }
    int col = n0 + lm;
    float bv = bc[col];
    #pragma unroll
    for (int r = 0; r < 4; ++r) {
        int row = row0 + lq * 4 + r;
        out[(size_t)row * 1024 + col] = acc[r] + bv;
    }
}

// ---------------------------------------------------------------- utilities
__global__ void cvt_f32_bf16(const float* __restrict__ in, u16* __restrict__ out, int n) {
    int i = blockIdx.x * 256 + threadIdx.x;
    if (i < n) out[i] = f2bf(in[i]);
}
__global__ void cvt_bf16_f32(const u16* __restrict__ in, float* __restrict__ out, int n) {
    int i = blockIdx.x * 256 + threadIdx.x;
    if (i < n) out[i] = bf2f(in[i]);
}
__global__ void copy_f32(const float* __restrict__ in, float* __restrict__ out, int n) {
    int i = blockIdx.x * 256 + threadIdx.x;
    if (i < n) out[i] = in[i];
}

// ---------------------------------------------------------------- launch
extern "C" void kernel_launch(void* const* d_in, const int* in_sizes, int n_in,
                              void* d_out, int out_size, void* d_ws, size_t ws_size,
                              hipStream_t stream)
{
    const float* x     = (const float*)d_in[0];   // [128,256,1024]
    const float* h0    = (const float*)d_in[1];   // [128,1024]
    const float* c0    = (const float*)d_in[2];   // [128,1024]
    const float* Wk    = (const float*)d_in[3];   // [1024,4096]
    const float* bk    = (const float*)d_in[4];   // [4096]
    const float* Wr    = (const float*)d_in[5];   // [1024,4096]
    const float* br    = (const float*)d_in[6];   // [4096]
    const float* alpha = (const float*)d_in[7];   // [1,4096]
    const float* beta1 = (const float*)d_in[8];   // [1,4096]
    const float* beta2 = (const float*)d_in[9];   // [1,4096]
    const float* Wc    = (const float*)d_in[10];  // [1024,1024]
    const float* bc    = (const float*)d_in[11];  // [1024]
    float* out = (float*)d_out;                   // out|h|c, each 128*1024 fp32

    // ws layout: small state, bf16 weights, then XP chunk (tc adaptive)
    char* p = (char*)d_ws;
    u16* h0bf = (u16*)p;  p += (size_t)B_SZ * UNITS * 2;        // 256 KB
    u16* hb0  = (u16*)p;  p += (size_t)B_SZ * UNITS * 2;        // 256 KB
    u16* hb1  = (u16*)p;  p += (size_t)B_SZ * UNITS * 2;        // 256 KB
    float* cbuf = (float*)p; p += (size_t)B_SZ * UNITS * 4;     // 512 KB
    u16* WkT = (u16*)p;   p += (size_t)FOURU * D_IN * 2;        // 8 MB
    u16* WrT = (u16*)p;   p += (size_t)FOURU * UNITS * 2;       // 8 MB
    u16* WcT = (u16*)p;   p += (size_t)1024 * 1024 * 2;         // 2 MB
    u16* XPc = (u16*)p;   // bf16 [B_SZ*tc][4096]

    size_t fixedB = (size_t)(p - (char*)d_ws);
    int tc = 32, tcShift = 5;
    while (tc > 1 && fixedB + (size_t)B_SZ * tc * FOURU * 2 > ws_size) {
        tc >>= 1; tcShift -= 1;
    }

    // 1) weight transposes + fp32->bf16 convert
    transpose_cvt<<<dim3(FOURU / 32, D_IN / 32), 256, 0, stream>>>(Wk, WkT, D_IN, FOURU);
    transpose_cvt<<<dim3(FOURU / 32, UNITS / 32), 256, 0, stream>>>(Wr, WrT, UNITS, FOURU);
    transpose_cvt<<<dim3(1024 / 32, 1024 / 32), 256, 0, stream>>>(Wc, WcT, 1024, 1024);

    // 2) state init: h0 -> bf16, c0 -> fp32 scratch
    cvt_f32_bf16<<<(B_SZ * UNITS) / 256, 256, 0, stream>>>(h0, h0bf, B_SZ * UNITS);
    copy_f32<<<(B_SZ * UNITS) / 256, 256, 0, stream>>>(c0, cbuf, B_SZ * UNITS);

    // 3) recurrence, XP precomputed per tc-step chunk
    for (int t0 = 0; t0 < T_SZ; t0 += tc) {
        gemm_xp_chunk<<<dim3(tc, FOURU / 128), 256, 0, stream>>>(
            x, WkT, bk, XPc, t0, tcShift);
        for (int tt = 0; tt < tc; ++tt) {
            int t = t0 + tt;
            const u16* hsrc = (t == 0) ? h0bf : ((t & 1) ? hb0 : hb1);
            u16* hdst = (t & 1) ? hb1 : hb0;
            milstm_step<<<256, 256, 0, stream>>>(
                XPc + (size_t)tt * FOURU, WrT, br, alpha, beta1, beta2,
                hsrc, cbuf, hdst, cbuf, tc * FOURU);
        }
    }
    // T=256 even -> final h in hb1

    // 4) out = h @ Wc + bc ; emit h (bf16->f32), c (f32)
    gemm_out<<<128, 256, 0, stream>>>(hb1, WcT, bc, out);
    cvt_bf16_f32<<<(B_SZ * UNITS) / 256, 256, 0, stream>>>(hb1, out + B_SZ * UNITS, B_SZ * UNITS);
    copy_f32<<<(B_SZ * UNITS) / 256, 256, 0, stream>>>(cbuf, out + 2 * B_SZ * UNITS, B_SZ * UNITS);
}

// Round 5
// 4271.640 us; speedup vs baseline: 1.0834x; 1.0834x over previous
//
#include <hip/hip_runtime.h>

// MI-LSTM on MI355X (gfx950). I/O is FP32 (per reference dtypes); compute
// uses bf16 MFMA internally (test tolerance is bf16-grade: 1.156e-2).
// B=128, T=256, D_IN=1024, UNITS=1024, N_CLASS=1024.
//
// R5 change: milstm_step repartitioned so each WrT row is read by exactly ONE
// block per step (256 blocks x [4 u-cols x 4 gates], M=128). WrT slice (32 KB)
// staged in LDS once per step; h streamed through it (h is 256 KB -> L2-hot).
// WrT traffic per step: 64 MB -> 8 MB.

typedef unsigned short u16;
typedef __attribute__((ext_vector_type(8))) short short8;   // 8 x bf16 (4 VGPRs)
typedef __attribute__((ext_vector_type(4))) float f32x4;    // MFMA accumulator

#define B_SZ   128
#define T_SZ   256
#define D_IN   1024
#define UNITS  1024
#define FOURU  4096

__device__ __forceinline__ float bf2f(u16 h) {
    return __uint_as_float(((unsigned int)h) << 16);
}
__device__ __forceinline__ u16 f2bf(float f) {
    unsigned int u = __float_as_uint(f);
    u += 0x7fffu + ((u >> 16) & 1u);   // round-to-nearest-even
    return (u16)(u >> 16);
}
__device__ __forceinline__ float sigmoidf_(float x) {
    return 1.0f / (1.0f + __expf(-x));
}

// ---------------------------------------------------------------- transpose+cvt
// out[n][k] = bf16(in[k][n]);  in is fp32 [K][N] row-major.
__global__ __launch_bounds__(256) void transpose_cvt(
    const float* __restrict__ in, u16* __restrict__ out, int K, int N)
{
    __shared__ u16 t[32][33];
    int n0 = blockIdx.x * 32, k0 = blockIdx.y * 32;
    int c = threadIdx.x & 31, r = threadIdx.x >> 5;   // r in 0..7
    #pragma unroll
    for (int i = 0; i < 4; ++i) {
        int kk = r + i * 8;
        t[kk][c] = f2bf(in[(size_t)(k0 + kk) * N + n0 + c]);
    }
    __syncthreads();
    #pragma unroll
    for (int i = 0; i < 4; ++i) {
        int nn = r + i * 8;
        out[(size_t)(n0 + nn) * K + k0 + c] = t[c][nn];
    }
}

// ---------------------------------------------------------------- XP GEMM (one time-chunk)
// Cc[b*tc+tt][n] = bf16( x[b][t0+tt][:] @ Wk + bk ),  tt in [0,tc).
// X is fp32 (converted to bf16 during staging); Bt = WkT bf16 [4096][1024].
__global__ __launch_bounds__(256) void gemm_xp_chunk(
    const float* __restrict__ X, const u16* __restrict__ Bt,
    const float* __restrict__ bias, u16* __restrict__ Cc,
    int t0, int tcShift)
{
    __shared__ __align__(16) u16 As[128 * 40];
    __shared__ __align__(16) u16 Bs[128 * 40];
    int tid = threadIdx.x;
    int wave = tid >> 6, lane = tid & 63;
    int bm = blockIdx.x * 128;     // row' base, row' = b*tc + tt
    int bn = blockIdx.y * 128;
    int wm = (wave & 1) * 64, wn = (wave >> 1) * 64;
    int lm = lane & 15, lq = lane >> 4;
    int tcMask = (1 << tcShift) - 1;

    f32x4 acc[4][4] = {};

    for (int k0 = 0; k0 < D_IN; k0 += 32) {
        #pragma unroll
        for (int i = 0; i < 2; ++i) {
            int idx = tid + i * 256;
            int r = idx >> 2, q = idx & 3;
            int rowp = bm + r;
            int b = rowp >> tcShift;
            int tt = rowp & tcMask;
            const float* xs = &X[(size_t)(b * T_SZ + t0 + tt) * D_IN + k0 + q * 8];
            float4 f0 = *(const float4*)xs;
            float4 f1 = *(const float4*)(xs + 4);
            uint4 v;
            v.x = (unsigned)f2bf(f0.x) | ((unsigned)f2bf(f0.y) << 16);
            v.y = (unsigned)f2bf(f0.z) | ((unsigned)f2bf(f0.w) << 16);
            v.z = (unsigned)f2bf(f1.x) | ((unsigned)f2bf(f1.y) << 16);
            v.w = (unsigned)f2bf(f1.z) | ((unsigned)f2bf(f1.w) << 16);
            *(uint4*)&As[r * 40 + q * 8] = v;
            *(uint4*)&Bs[r * 40 + q * 8] =
                *(const uint4*)&Bt[(size_t)(bn + r) * D_IN + k0 + q * 8];
        }
        __syncthreads();
        short8 af[4], bf[4];
        #pragma unroll
        for (int t = 0; t < 4; ++t) {
            af[t] = *(const short8*)&As[(wm + t * 16 + lm) * 40 + lq * 8];
            bf[t] = *(const short8*)&Bs[(wn + t * 16 + lm) * 40 + lq * 8];
        }
        #pragma unroll
        for (int mt = 0; mt < 4; ++mt)
            #pragma unroll
            for (int nt = 0; nt < 4; ++nt)
                acc[mt][nt] = __builtin_amdgcn_mfma_f32_16x16x32_bf16(
                    af[mt], bf[nt], acc[mt][nt], 0, 0, 0);
        __syncthreads();
    }

    #pragma unroll
    for (int mt = 0; mt < 4; ++mt) {
        #pragma unroll
        for (int nt = 0; nt < 4; ++nt) {
            int col = bn + wn + nt * 16 + lm;
            float bv = bias[col];
            #pragma unroll
            for (int r = 0; r < 4; ++r) {
                int rowp = bm + wm + mt * 16 + lq * 4 + r;
                Cc[(size_t)rowp * FOURU + col] = f2bf(acc[mt][nt][r] + bv);
            }
        }
    }
}

// ---------------------------------------------------------------- LSTM step (R5)
// 256 blocks x 256 threads. Block owns u0=blockIdx*4: 4 u-cols x 4 gates
// = 16 n-cols (LDS row l = g*4+j  ->  n = g*1024 + u0 + j), M = all 128 rows.
// WrT slice (16 rows x 1024 k, bf16) staged to LDS once; h read from global
// (L2-hot, 256 KB). Wave w computes m-tiles {w, w+4}. Epilogue fuses MI gates.
__global__ __launch_bounds__(256) void milstm_step(
    const u16* __restrict__ XPtt,    // chunk base + tt*4096; batch stride bStride
    const u16* __restrict__ WrT,     // [4096][1024] bf16
    const float* __restrict__ br,
    const float* __restrict__ alpha,
    const float* __restrict__ beta1,
    const float* __restrict__ beta2,
    const u16* __restrict__ h_in,    // [128][1024] bf16
    const float* __restrict__ c_in,  // [128][1024] f32
    u16* __restrict__ h_out,
    float* __restrict__ c_out,
    int bStride)
{
    __shared__ __align__(16) u16 WrS[16 * 1032];   // +8 pad: 2-way banks only
    __shared__ float zbuf[16][132];                // [n-local][m] hp partials
    __shared__ float brS[16], alS[16], b1S[16], b2S[16];

    int tid = threadIdx.x;
    int wave = tid >> 6, lane = tid & 63;
    int lm = lane & 15, lq = lane >> 4;
    int u0 = blockIdx.x * 4;

    // stage WrT slice: 16 rows x 1024 bf16 = 2048 uint4
    #pragma unroll
    for (int i = 0; i < 8; ++i) {
        int idx = i * 256 + tid;
        int l = idx >> 7, q = idx & 127;
        int n = ((l >> 2) << 10) + u0 + (l & 3);
        *(uint4*)&WrS[l * 1032 + q * 8] = *(const uint4*)&WrT[(size_t)n * 1024 + q * 8];
    }
    if (tid < 16) {
        int n = ((tid >> 2) << 10) + u0 + (tid & 3);
        brS[tid] = br[n]; alS[tid] = alpha[n];
        b1S[tid] = beta1[n]; b2S[tid] = beta2[n];
    }
    __syncthreads();

    // hp = h @ Wr-slice: wave handles m-tiles {wave, wave+4}
    const u16* A0 = &h_in[(size_t)(wave * 16 + lm) * UNITS];
    const u16* A1 = &h_in[(size_t)((wave + 4) * 16 + lm) * UNITS];
    const u16* Bl = &WrS[lm * 1032];
    f32x4 acc0 = {}, acc1 = {};
    #pragma unroll 8
    for (int k0 = 0; k0 < UNITS; k0 += 32) {
        short8 b  = *(const short8*)&Bl[k0 + lq * 8];
        short8 a0 = *(const short8*)&A0[k0 + lq * 8];
        short8 a1 = *(const short8*)&A1[k0 + lq * 8];
        acc0 = __builtin_amdgcn_mfma_f32_16x16x32_bf16(a0, b, acc0, 0, 0, 0);
        acc1 = __builtin_amdgcn_mfma_f32_16x16x32_bf16(a1, b, acc1, 0, 0, 0);
    }
    #pragma unroll
    for (int r = 0; r < 4; ++r) {
        zbuf[lm][wave * 16 + lq * 4 + r]       = acc0[r];
        zbuf[lm][(wave + 4) * 16 + lq * 4 + r] = acc1[r];
    }
    __syncthreads();

    // fused MI gates: 512 items = 128 rows x 4 u-cols
    #pragma unroll
    for (int e = 0; e < 2; ++e) {
        int item = tid + e * 256;
        int row = item >> 2, j = item & 3;
        float z[4];
        #pragma unroll
        for (int g = 0; g < 4; ++g) {
            int l = g * 4 + j;
            float hp = zbuf[l][row] + brS[l];
            float xp = bf2f(XPtt[(size_t)row * bStride + ((g << 10) + u0 + j)]);
            z[g] = alS[l] * xp * hp + b1S[l] * xp + b2S[l] * hp;
        }
        size_t gi = (size_t)row * UNITS + u0 + j;
        float c = c_in[gi];
        float cn = tanhf(z[2]) * sigmoidf_(z[0]) + c * sigmoidf_(z[1]);
        c_out[gi] = cn;
        h_out[gi] = f2bf(tanhf(cn) * sigmoidf_(z[3]));
    }
}

// ---------------------------------------------------------------- final GEMM
// out[128][1024] = h @ Wc + bc (fp32 out); WcT bf16 [1024][1024].
__global__ __launch_bounds__(256) void gemm_out(
    const u16* __restrict__ h, const u16* __restrict__ WcT,
    const float* __restrict__ bc, float* __restrict__ out)
{
    int tid = threadIdx.x;
    int wave = tid >> 6, lane = tid & 63;
    int bx = blockIdx.x;               // 128 blocks: 8 row-tiles x 16 col-grps
    int row0 = (bx & 7) * 16;
    int n0 = (bx >> 3) * 64 + wave * 16;
    int lm = lane & 15, lq = lane >> 4;

    f32x4 acc = {};
    const u16* Arow = &h[(size_t)(row0 + lm) * UNITS];
    const u16* Brow = &WcT[(size_t)(n0 + lm) * UNITS];
    #pragma unroll 8
    for (int k0 = 0; k0 < UNITS; k0 += 32) {
        short8 a = *(const short8*)&Arow[k0 + lq * 8];
        short8 b = *(const short8*)&Brow[k0 + lq * 8];
        acc = __builtin_amdgcn_mfma_f32_16x16x32_bf16(a, b, acc, 0, 0, 0);
    }
    int col = n0 + lm;
    float bv = bc[col];
    #pragma unroll
    for (int r = 0; r < 4; ++r) {
        int row = row0 + lq * 4 + r;
        out[(size_t)row * 1024 + col] = acc[r] + bv;
    }
}

// ---------------------------------------------------------------- utilities
__global__ void cvt_f32_bf16(const float* __restrict__ in, u16* __restrict__ out, int n) {
    int i = blockIdx.x * 256 + threadIdx.x;
    if (i < n) out[i] = f2bf(in[i]);
}
__global__ void cvt_bf16_f32(const u16* __restrict__ in, float* __restrict__ out, int n) {
    int i = blockIdx.x * 256 + threadIdx.x;
    if (i < n) out[i] = bf2f(in[i]);
}
__global__ void copy_f32(const float* __restrict__ in, float* __restrict__ out, int n) {
    int i = blockIdx.x * 256 + threadIdx.x;
    if (i < n) out[i] = in[i];
}

// ---------------------------------------------------------------- launch
extern "C" void kernel_launch(void* const* d_in, const int* in_sizes, int n_in,
                              void* d_out, int out_size, void* d_ws, size_t ws_size,
                              hipStream_t stream)
{
    const float* x     = (const float*)d_in[0];   // [128,256,1024]
    const float* h0    = (const float*)d_in[1];   // [128,1024]
    const float* c0    = (const float*)d_in[2];   // [128,1024]
    const float* Wk    = (const float*)d_in[3];   // [1024,4096]
    const float* bk    = (const float*)d_in[4];   // [4096]
    const float* Wr    = (const float*)d_in[5];   // [1024,4096]
    const float* br    = (const float*)d_in[6];   // [4096]
    const float* alpha = (const float*)d_in[7];   // [1,4096]
    const float* beta1 = (const float*)d_in[8];   // [1,4096]
    const float* beta2 = (const float*)d_in[9];   // [1,4096]
    const float* Wc    = (const float*)d_in[10];  // [1024,1024]
    const float* bc    = (const float*)d_in[11];  // [1024]
    float* out = (float*)d_out;                   // out|h|c, each 128*1024 fp32

    // ws layout: small state, bf16 weights, then XP chunk (tc adaptive)
    char* p = (char*)d_ws;
    u16* h0bf = (u16*)p;  p += (size_t)B_SZ * UNITS * 2;
    u16* hb0  = (u16*)p;  p += (size_t)B_SZ * UNITS * 2;
    u16* hb1  = (u16*)p;  p += (size_t)B_SZ * UNITS * 2;
    float* cbuf = (float*)p; p += (size_t)B_SZ * UNITS * 4;
    u16* WkT = (u16*)p;   p += (size_t)FOURU * D_IN * 2;
    u16* WrT = (u16*)p;   p += (size_t)FOURU * UNITS * 2;
    u16* WcT = (u16*)p;   p += (size_t)1024 * 1024 * 2;
    u16* XPc = (u16*)p;   // bf16 [B_SZ*tc][4096]

    size_t fixedB = (size_t)(p - (char*)d_ws);
    int tc = 32, tcShift = 5;
    while (tc > 1 && fixedB + (size_t)B_SZ * tc * FOURU * 2 > ws_size) {
        tc >>= 1; tcShift -= 1;
    }

    // 1) weight transposes + fp32->bf16 convert
    transpose_cvt<<<dim3(FOURU / 32, D_IN / 32), 256, 0, stream>>>(Wk, WkT, D_IN, FOURU);
    transpose_cvt<<<dim3(FOURU / 32, UNITS / 32), 256, 0, stream>>>(Wr, WrT, UNITS, FOURU);
    transpose_cvt<<<dim3(1024 / 32, 1024 / 32), 256, 0, stream>>>(Wc, WcT, 1024, 1024);

    // 2) state init: h0 -> bf16, c0 -> fp32 scratch
    cvt_f32_bf16<<<(B_SZ * UNITS) / 256, 256, 0, stream>>>(h0, h0bf, B_SZ * UNITS);
    copy_f32<<<(B_SZ * UNITS) / 256, 256, 0, stream>>>(c0, cbuf, B_SZ * UNITS);

    // 3) recurrence, XP precomputed per tc-step chunk
    for (int t0 = 0; t0 < T_SZ; t0 += tc) {
        gemm_xp_chunk<<<dim3(tc, FOURU / 128), 256, 0, stream>>>(
            x, WkT, bk, XPc, t0, tcShift);
        for (int tt = 0; tt < tc; ++tt) {
            int t = t0 + tt;
            const u16* hsrc = (t == 0) ? h0bf : ((t & 1) ? hb0 : hb1);
            u16* hdst = (t & 1) ? hb1 : hb0;
            milstm_step<<<256, 256, 0, stream>>>(
                XPc + (size_t)tt * FOURU, WrT, br, alpha, beta1, beta2,
                hsrc, cbuf, hdst, cbuf, tc * FOURU);
        }
    }
    // T=256 even -> final h in hb1

    // 4) out = h @ Wc + bc ; emit h (bf16->f32), c (f32)
    gemm_out<<<128, 256, 0, stream>>>(hb1, WcT, bc, out);
    cvt_bf16_f32<<<(B_SZ * UNITS) / 256, 256, 0, stream>>>(hb1, out + B_SZ * UNITS, B_SZ * UNITS);
    copy_f32<<<(B_SZ * UNITS) / 256, 256, 0, stream>>>(cbuf, out + 2 * B_SZ * UNITS, B_SZ * UNITS);
}